// Round 5
// baseline (145.546 us; speedup 1.0000x reference)
//
#include <hip/hip_runtime.h>

// DFMB PSROIAlign — separable (rank-1) weights + phase-split sides.
//
// Per (roi,bin) the 16 subsamples live in a 3x3 pixel patch; per-pixel weight
// W[p][q] = AY[p]*AX[q] - BY[p]*BX[q], count = cntY*cntX (bilinear, keep-gate
// and bad11-gate all separable in ih/iw).
//
// R4 lesson: latency-bound (VALUBusy 24%, occupancy 25%, nothing saturated).
// 38.9KB LDS -> ~2-4 blocks/CU and 4 serialized L2-gather batches per thread.
// R5: RPB=8 -> LDS 19.3KB (tile 8x491 + sides 14x8x8) -> ~7 blocks/CU, 32
// slots/roi -> <=2 bins/thread, and phase 2 is branch-free (invalid bins get
// zero weights + clamped addresses) so load batches aren't split by branches.

#define NC 10
#define NBIN 49
#define FH 34
#define FW 34
#define PLANE (FH * FW)
#define CSTRIDE 16   // floats per pixel in ftT (64B = one cache line)
#define RPB 8        // rois per block
#define TSTRIDE 491  // out-tile row stride (odd -> conflict-free flush)
#define NSIDE 14

__global__ __launch_bounds__(256) void prep_kernel(
    const float* __restrict__ ft, float* __restrict__ ftT)
{
    const int p = blockIdx.x * 256 + threadIdx.x;  // over 49*1156 pixels
    if (p >= NBIN * PLANE) return;
    float v[NC];
#pragma unroll
    for (int c = 0; c < NC; ++c) v[c] = ft[c * (NBIN * PLANE) + p];
    float4* d = reinterpret_cast<float4*>(ftT + (size_t)p * CSTRIDE);
    d[0] = make_float4(v[0], v[1], v[2], v[3]);
    d[1] = make_float4(v[4], v[5], v[6], v[7]);
    d[2] = make_float4(v[8], v[9], 0.f, 0.f);
}

__global__ __launch_bounds__(256) void main_kernel(
    const float* __restrict__ rois, const float* __restrict__ ftT,
    const float* __restrict__ ft, float* __restrict__ out, int N, int use_t)
{
    __shared__ float sides[NSIDE][RPB][8];  // 3.5 KB
    __shared__ float tile[RPB][TSTRIDE];    // 15.7 KB

    const int r = threadIdx.x & (RPB - 1);  // roi within block
    const int s = threadIdx.x >> 3;         // slot 0..31
    const int n = blockIdx.x * RPB + r;
    const bool valid = (n < N);

    float rsw = 0.f, rsh = 0.f, rew = 0.f, reh = 0.f;
    if (valid) {
        rsw = rois[n * 5 + 1] * 0.125f;  // /STRIDE(8), exact pow2
        rsh = rois[n * 5 + 2] * 0.125f;
        rew = rois[n * 5 + 3] * 0.125f;
        reh = rois[n * 5 + 4] * 0.125f;
    }
    // Explicit _rn chain: floor/ceil/compare inputs must bit-match numpy fp32.
    float rheight = __fsub_rn(reh, rsh);
    if (!(rheight > 0.1f)) rheight = 0.1f;
    float rwidth = __fsub_rn(rew, rsw);
    if (!(rwidth > 0.1f)) rwidth = 0.1f;
    const float bsh   = __fdiv_rn(rheight, 7.0f);
    const float bsw   = __fdiv_rn(rwidth, 7.0f);
    const float sub_h = __fdiv_rn(bsh, 4.0f);
    const float sub_w = __fdiv_rn(bsw, 4.0f);

    // ---- phase 1: one axis-side per slot (slots 0..13 active) ----
    if (s < NSIDE) {
        const bool isY = (s < 7);
        const int  k   = isY ? s : s - 7;
        const float st = isY ? rsh : rsw;
        const float bs = isY ? bsh : bsw;
        const float sb = isY ? sub_h : sub_w;
        const float start = floorf(__fadd_rn(st, __fmul_rn((float)k, bs)));

        float A[3] = {0.f, 0.f, 0.f}, B[3] = {0.f, 0.f, 0.f};
        float cnt = 0.f;
        int P0 = 0;
#pragma unroll
        for (int i = 0; i < 4; ++i) {
            const float h = __fadd_rn(start, __fmul_rn((float)i + 0.5f, sb));
            const bool ok = (h > -1.0f) && (h < 34.0f);
            const int p1 = (int)floorf(h);
            const int p2 = (int)ceilf(h);
            const bool v1 = (p1 >= 0) && (p1 < 34);
            const bool v2 = (p2 >= 0) && (p2 < 34);
            const int p1c = min(max(p1, 0), 33);
            const int p2c = min(max(p2, 0), 33);
            const float d = __fsub_rn(h, (float)p1c);  // vs CLIPPED corner
            if (i == 0) P0 = p1c;                      // min (h increasing)
            const int i1 = p1c - P0, i2 = p2c - P0;    // in {0,1,2}
            const float t1 = ok ? (1.0f - d) : 0.0f;
            const float t2 = ok ? d : 0.0f;
            // bad11 = (!x1v || !x2v) && (y1v || y2v): X carries "invalid",
            // Y carries "valid".
            const bool bsel = isY ? (v1 || v2) : ((!v1) || (!v2));
            const float tb = (ok && bsel) ? (1.0f - d) : 0.0f;
            cnt += ok ? 1.0f : 0.0f;
#pragma unroll
            for (int p = 0; p < 3; ++p) {
                A[p] += (i1 == p) ? t1 : 0.0f;
                A[p] += (i2 == p) ? t2 : 0.0f;
                B[p] += (i1 == p) ? tb : 0.0f;
            }
        }
        float* sp = &sides[s][r][0];
        sp[0] = A[0]; sp[1] = A[1]; sp[2] = A[2];
        sp[3] = B[0]; sp[4] = B[1]; sp[5] = B[2];
        sp[6] = cnt;  sp[7] = (float)P0;
    }
    __syncthreads();

    // ---- phase 2: <=2 bins per thread, fully branch-free load batches ----
#pragma unroll
    for (int j = 0; j < 2; ++j) {
        const int bin0 = j * 32 + s;               // 0..63
        const bool live = valid && (bin0 < NBIN);
        const int bin = min(bin0, NBIN - 1);       // clamp for safe addressing
        const float wmask = live ? 1.0f : 0.0f;    // zero weights if dead

        const int ph = bin / 7;
        const int pw = bin - ph * 7;

        const float4 ya = *(const float4*)&sides[ph][r][0];
        const float4 yb = *(const float4*)&sides[ph][r][4];
        const float4 xa = *(const float4*)&sides[7 + pw][r][0];
        const float4 xb = *(const float4*)&sides[7 + pw][r][4];
        const float AY[3] = {ya.x, ya.y, ya.z};
        const float BY[3] = {ya.w, yb.x, yb.y};
        const float cntY  = yb.z;
        const int   Y0    = (int)yb.w;
        const float AX[3] = {xa.x * wmask, xa.y * wmask, xa.z * wmask};
        const float BX[3] = {xa.w * wmask, xb.x * wmask, xb.y * wmask};
        const float cntX  = xb.z;
        const int   X0    = (int)xb.w;

        const int binbase = bin * PLANE;
        const int rowo[3] = {binbase + Y0 * FW,
                             binbase + min(Y0 + 1, FH - 1) * FW,
                             binbase + min(Y0 + 2, FH - 1) * FW};
        const int colo[3] = {X0, min(X0 + 1, FW - 1), min(X0 + 2, FW - 1)};

        float wgt[9];
        int   off[9];
#pragma unroll
        for (int p = 0; p < 3; ++p)
#pragma unroll
            for (int q = 0; q < 3; ++q) {
                const float w = AY[p] * AX[q] - BY[p] * BX[q];
                wgt[3 * p + q] = w;
                // zero-weight -> shared dummy pixel (plane origin): loads stay
                // batched, masked lanes share one hot line.
                off[3 * p + q] = (w != 0.0f) ? (rowo[p] + colo[q]) : binbase;
            }

        float sum[NC];
#pragma unroll
        for (int c = 0; c < NC; ++c) sum[c] = 0.f;

        if (use_t) {
#pragma unroll
            for (int k = 0; k < 9; ++k) {
                const float* pix = ftT + (size_t)off[k] * CSTRIDE;
                const float4 a  = *(const float4*)pix;
                const float4 b  = *(const float4*)(pix + 4);
                const float2 c2 = *(const float2*)(pix + 8);
                const float w = wgt[k];
                sum[0] = fmaf(w, a.x, sum[0]);
                sum[1] = fmaf(w, a.y, sum[1]);
                sum[2] = fmaf(w, a.z, sum[2]);
                sum[3] = fmaf(w, a.w, sum[3]);
                sum[4] = fmaf(w, b.x, sum[4]);
                sum[5] = fmaf(w, b.y, sum[5]);
                sum[6] = fmaf(w, b.z, sum[6]);
                sum[7] = fmaf(w, b.w, sum[7]);
                sum[8] = fmaf(w, c2.x, sum[8]);
                sum[9] = fmaf(w, c2.y, sum[9]);
            }
        } else {
#pragma unroll
            for (int k = 0; k < 9; ++k) {
                const float w = wgt[k];
#pragma unroll
                for (int c = 0; c < NC; ++c)
                    sum[c] = fmaf(w, ft[c * (NBIN * PLANE) + off[k]], sum[c]);
            }
        }

        const float cnt = cntY * cntX;
        const float inv = (cnt > 0.0f) ? __fdiv_rn(1.0f, cnt) : 1.0f;
        if (live) {
            float* tp = &tile[r][0];
#pragma unroll
            for (int c = 0; c < NC; ++c) tp[c * NBIN + bin] = sum[c] * inv;
        }
    }

    __syncthreads();

    // Coalesced flush: 8 rois x 490 contiguous floats each.
    const int n0 = blockIdx.x * RPB;
    for (int i = threadIdx.x; i < RPB * (NC * NBIN); i += 256) {
        const int row = i / (NC * NBIN);
        const int col = i - row * (NC * NBIN);
        const int n2 = n0 + row;
        if (n2 < N) out[(size_t)n2 * (NC * NBIN) + col] = tile[row][col];
    }
}

extern "C" void kernel_launch(void* const* d_in, const int* in_sizes, int n_in,
                              void* d_out, int out_size, void* d_ws, size_t ws_size,
                              hipStream_t stream) {
    const float* ft   = (const float*)d_in[0];
    const float* rois = (const float*)d_in[1];
    float* out        = (float*)d_out;
    const int N = in_sizes[1] / 5;

    const size_t need = (size_t)NBIN * PLANE * CSTRIDE * sizeof(float);  // 3.63 MB
    const int use_t = (ws_size >= need) ? 1 : 0;
    float* ftT = (float*)d_ws;

    if (use_t) {
        const int npix = NBIN * PLANE;
        prep_kernel<<<(npix + 255) / 256, 256, 0, stream>>>(ft, ftT);
    }
    main_kernel<<<(N + RPB - 1) / RPB, 256, 0, stream>>>(rois, ftT, ft, out, N, use_t);
}

// Round 6
// 126.523 us; speedup vs baseline: 1.1504x; 1.1504x over previous
//
#include <hip/hip_runtime.h>

// DFMB PSROIAlign — separable (rank-1) weights + phase-split sides.
//
// Per (roi,bin) the 16 subsamples live in a 3x3 pixel patch; per-pixel weight
// W[p][q] = AY[p]*AX[q] - BY[p]*BX[q], count = cntY*cntX (bilinear, keep-gate
// and bad11-gate all separable in ih/iw).
//
// R5 lesson: splitting blocks smaller regressed (occupancy was not LDS-capped;
// dead-lane work + overhead amortization hurt). R4's real limiter: VGPR=68
// forces the compiler to chunk each bin's 27-load patch batch into ~2-pixel
// groups -> ~4-9 serialized L2 round-trips per bin. R6 = R4 structure +
// explicit 9-pixel register arrays + __launch_bounds__(256,2) (VGPR budget
// 256) so all 27 loads issue behind ONE waitcnt per bin.

#define NC 10
#define NBIN 49
#define FH 34
#define FW 34
#define PLANE (FH * FW)
#define CSTRIDE 16   // floats per pixel in ftT (64B = one cache line)
#define RPB 16       // rois per block
#define TSTRIDE 491  // out-tile row stride (odd -> conflict-free flush)
#define NSIDE 14

__global__ __launch_bounds__(256) void prep_kernel(
    const float* __restrict__ ft, float* __restrict__ ftT)
{
    const int p = blockIdx.x * 256 + threadIdx.x;  // over 49*1156 pixels
    if (p >= NBIN * PLANE) return;
    float v[NC];
#pragma unroll
    for (int c = 0; c < NC; ++c) v[c] = ft[c * (NBIN * PLANE) + p];
    float4* d = reinterpret_cast<float4*>(ftT + (size_t)p * CSTRIDE);
    d[0] = make_float4(v[0], v[1], v[2], v[3]);
    d[1] = make_float4(v[4], v[5], v[6], v[7]);
    d[2] = make_float4(v[8], v[9], 0.f, 0.f);
}

__global__ __launch_bounds__(256, 2) void main_kernel(
    const float* __restrict__ rois, const float* __restrict__ ftT,
    const float* __restrict__ ft, float* __restrict__ out, int N, int use_t)
{
    __shared__ float sides[NSIDE][RPB][8];  // 7 KB
    __shared__ float tile[RPB][TSTRIDE];    // 31.4 KB

    const int r = threadIdx.x & (RPB - 1);  // roi within block
    const int s = threadIdx.x >> 4;         // slot 0..15
    const int n = blockIdx.x * RPB + r;
    const bool valid = (n < N);

    float rsw = 0.f, rsh = 0.f, rew = 0.f, reh = 0.f;
    if (valid) {
        rsw = rois[n * 5 + 1] * 0.125f;  // /STRIDE(8), exact pow2
        rsh = rois[n * 5 + 2] * 0.125f;
        rew = rois[n * 5 + 3] * 0.125f;
        reh = rois[n * 5 + 4] * 0.125f;
    }
    // Explicit _rn chain: floor/ceil/compare inputs must bit-match numpy fp32.
    float rheight = __fsub_rn(reh, rsh);
    if (!(rheight > 0.1f)) rheight = 0.1f;
    float rwidth = __fsub_rn(rew, rsw);
    if (!(rwidth > 0.1f)) rwidth = 0.1f;
    const float bsh   = __fdiv_rn(rheight, 7.0f);
    const float bsw   = __fdiv_rn(rwidth, 7.0f);
    const float sub_h = __fdiv_rn(bsh, 4.0f);
    const float sub_w = __fdiv_rn(bsw, 4.0f);

    // ---- phase 1: one axis-side per slot (slots 0..13 active) ----
    if (s < NSIDE) {
        const bool isY = (s < 7);
        const int  k   = isY ? s : s - 7;
        const float st = isY ? rsh : rsw;
        const float bs = isY ? bsh : bsw;
        const float sb = isY ? sub_h : sub_w;
        const float start = floorf(__fadd_rn(st, __fmul_rn((float)k, bs)));

        float A[3] = {0.f, 0.f, 0.f}, B[3] = {0.f, 0.f, 0.f};
        float cnt = 0.f;
        int P0 = 0;
#pragma unroll
        for (int i = 0; i < 4; ++i) {
            const float h = __fadd_rn(start, __fmul_rn((float)i + 0.5f, sb));
            const bool ok = (h > -1.0f) && (h < 34.0f);
            const int p1 = (int)floorf(h);
            const int p2 = (int)ceilf(h);
            const bool v1 = (p1 >= 0) && (p1 < 34);
            const bool v2 = (p2 >= 0) && (p2 < 34);
            const int p1c = min(max(p1, 0), 33);
            const int p2c = min(max(p2, 0), 33);
            const float d = __fsub_rn(h, (float)p1c);  // vs CLIPPED corner
            if (i == 0) P0 = p1c;                      // min (h increasing)
            const int i1 = p1c - P0, i2 = p2c - P0;    // in {0,1,2}
            const float t1 = ok ? (1.0f - d) : 0.0f;
            const float t2 = ok ? d : 0.0f;
            // bad11 = (!x1v || !x2v) && (y1v || y2v): X carries "invalid",
            // Y carries "valid".
            const bool bsel = isY ? (v1 || v2) : ((!v1) || (!v2));
            const float tb = (ok && bsel) ? (1.0f - d) : 0.0f;
            cnt += ok ? 1.0f : 0.0f;
#pragma unroll
            for (int p = 0; p < 3; ++p) {
                A[p] += (i1 == p) ? t1 : 0.0f;
                A[p] += (i2 == p) ? t2 : 0.0f;
                B[p] += (i1 == p) ? tb : 0.0f;
            }
        }
        float* sp = &sides[s][r][0];
        sp[0] = A[0]; sp[1] = A[1]; sp[2] = A[2];
        sp[3] = B[0]; sp[4] = B[1]; sp[5] = B[2];
        sp[6] = cnt;  sp[7] = (float)P0;
    }
    __syncthreads();

    // ---- phase 2: 4 bins/thread; per bin ALL 27 loads batched in regs ----
#pragma unroll
    for (int j = 0; j < 4; ++j) {
        const int bin = j * RPB + s;
        if (valid && bin < NBIN) {
            const int ph = bin / 7;
            const int pw = bin - ph * 7;

            const float4 ya = *(const float4*)&sides[ph][r][0];
            const float4 yb = *(const float4*)&sides[ph][r][4];
            const float4 xa = *(const float4*)&sides[7 + pw][r][0];
            const float4 xb = *(const float4*)&sides[7 + pw][r][4];
            const float AY[3] = {ya.x, ya.y, ya.z};
            const float BY[3] = {ya.w, yb.x, yb.y};
            const float cntY  = yb.z;
            const int   Y0    = (int)yb.w;
            const float AX[3] = {xa.x, xa.y, xa.z};
            const float BX[3] = {xa.w, xb.x, xb.y};
            const float cntX  = xb.z;
            const int   X0    = (int)xb.w;

            const int binbase = bin * PLANE;
            const int rowo[3] = {binbase + Y0 * FW,
                                 binbase + min(Y0 + 1, FH - 1) * FW,
                                 binbase + min(Y0 + 2, FH - 1) * FW};
            const int colo[3] = {X0, min(X0 + 1, FW - 1), min(X0 + 2, FW - 1)};

            float wgt[9];
            int   off[9];
#pragma unroll
            for (int p = 0; p < 3; ++p)
#pragma unroll
                for (int q = 0; q < 3; ++q) {
                    const float w = AY[p] * AX[q] - BY[p] * BX[q];
                    wgt[3 * p + q] = w;
                    // zero-weight -> shared dummy pixel (plane origin): loads
                    // stay batched, masked lanes share one hot line.
                    off[3 * p + q] = (w != 0.0f) ? (rowo[p] + colo[q]) : binbase;
                }

            float sum[NC];
#pragma unroll
            for (int c = 0; c < NC; ++c) sum[c] = 0.f;

            if (use_t) {
                // Full 9-pixel batch in registers: one waitcnt per bin, not
                // one per 2-pixel chunk (R4's VGPR=68 forced chunking).
                float4 pa[9], pb[9];
                float2 pc[9];
#pragma unroll
                for (int k = 0; k < 9; ++k) {
                    const float* pix = ftT + (size_t)off[k] * CSTRIDE;
                    pa[k] = *(const float4*)pix;
                    pb[k] = *(const float4*)(pix + 4);
                    pc[k] = *(const float2*)(pix + 8);
                }
#pragma unroll
                for (int k = 0; k < 9; ++k) {
                    const float w = wgt[k];
                    sum[0] = fmaf(w, pa[k].x, sum[0]);
                    sum[1] = fmaf(w, pa[k].y, sum[1]);
                    sum[2] = fmaf(w, pa[k].z, sum[2]);
                    sum[3] = fmaf(w, pa[k].w, sum[3]);
                    sum[4] = fmaf(w, pb[k].x, sum[4]);
                    sum[5] = fmaf(w, pb[k].y, sum[5]);
                    sum[6] = fmaf(w, pb[k].z, sum[6]);
                    sum[7] = fmaf(w, pb[k].w, sum[7]);
                    sum[8] = fmaf(w, pc[k].x, sum[8]);
                    sum[9] = fmaf(w, pc[k].y, sum[9]);
                }
            } else {
#pragma unroll
                for (int k = 0; k < 9; ++k) {
                    const float w = wgt[k];
#pragma unroll
                    for (int c = 0; c < NC; ++c)
                        sum[c] = fmaf(w, ft[c * (NBIN * PLANE) + off[k]], sum[c]);
                }
            }

            const float cnt = cntY * cntX;
            const float inv = (cnt > 0.0f) ? __fdiv_rn(1.0f, cnt) : 1.0f;
            float* tp = &tile[r][0];
#pragma unroll
            for (int c = 0; c < NC; ++c) tp[c * NBIN + bin] = sum[c] * inv;
        }
    }

    __syncthreads();

    // Coalesced flush: 16 rois x 490 contiguous floats each.
    const int n0 = blockIdx.x * RPB;
    for (int i = threadIdx.x; i < RPB * (NC * NBIN); i += 256) {
        const int row = i / (NC * NBIN);
        const int col = i - row * (NC * NBIN);
        const int n2 = n0 + row;
        if (n2 < N) out[(size_t)n2 * (NC * NBIN) + col] = tile[row][col];
    }
}

extern "C" void kernel_launch(void* const* d_in, const int* in_sizes, int n_in,
                              void* d_out, int out_size, void* d_ws, size_t ws_size,
                              hipStream_t stream) {
    const float* ft   = (const float*)d_in[0];
    const float* rois = (const float*)d_in[1];
    float* out        = (float*)d_out;
    const int N = in_sizes[1] / 5;

    const size_t need = (size_t)NBIN * PLANE * CSTRIDE * sizeof(float);  // 3.63 MB
    const int use_t = (ws_size >= need) ? 1 : 0;
    float* ftT = (float*)d_ws;

    if (use_t) {
        const int npix = NBIN * PLANE;
        prep_kernel<<<(npix + 255) / 256, 256, 0, stream>>>(ft, ftT);
    }
    main_kernel<<<(N + RPB - 1) / RPB, 256, 0, stream>>>(rois, ftT, ft, out, N, use_t);
}